// Round 1
// baseline (340.401 us; speedup 1.0000x reference)
//
#include <hip/hip_runtime.h>

// Problem constants
#define NB 8192     // batch
#define IC 32       // input capsules
#define ID 288      // input dims (K)
#define OD16 160    // OUT_CAPS*OUT_DIMS (N)

typedef __attribute__((ext_vector_type(8))) short bf16x8;
typedef __attribute__((ext_vector_type(4))) float f32x4;
typedef __attribute__((ext_vector_type(8))) unsigned short u16x8;

__device__ __forceinline__ unsigned short f2bf(float f) {
    unsigned int u = __builtin_bit_cast(unsigned int, f);
    u = u + 0x7fffu + ((u >> 16) & 1u);   // round-to-nearest-even
    return (unsigned short)(u >> 16);
}
__device__ __forceinline__ float bf2f(unsigned short h) {
    return __builtin_bit_cast(float, ((unsigned int)h) << 16);
}

// ---------------------------------------------------------------------------
// K0: build Wt[c][ktile][n][64] (bf16, transposed, K padded 288->320) and
//     zero b (320 f32) + a (320 f32), which are contiguous at `ba`.
// ---------------------------------------------------------------------------
__global__ __launch_bounds__(256) void prep_kernel(const float* __restrict__ W,
                                                   unsigned short* __restrict__ Wt,
                                                   float* __restrict__ ba) {
    const long idx = (long)blockIdx.x * 256 + threadIdx.x;
    if (idx < 640) ba[idx] = 0.f;
    const long ngran = 32L * 5 * OD16 * 8;  // 204800 granules of 8 bf16
    for (long gq = idx; gq < ngran; gq += (long)gridDim.x * 256) {
        int c = (int)(gq / 6400);
        int rem = (int)(gq - (long)c * 6400);
        int kt = rem / 1280;
        int rem2 = rem - kt * 1280;
        int n = rem2 >> 3;
        int g = rem2 & 7;
        u16x8 out8;
        #pragma unroll
        for (int e = 0; e < 8; ++e) {
            int ksrc = kt * 64 + g * 8 + e;
            float val = (ksrc < ID) ? W[((long)c * ID + ksrc) * OD16 + n] : 0.f;
            out8[e] = f2bf(val);
        }
        *(u16x8*)(Wt + gq * 8) = out8;
    }
}

// ---------------------------------------------------------------------------
// K1: per-capsule GEMM  u_hat[b][c][od] = data[b][c][:] @ W[c][:][od]  (bf16 MFMA)
// Block: 256 thr (4 waves), tile 128(M) x 160(N), BK=64, K=288 -> 4.5 stages.
// LDS rows are 128B with XOR swizzle ((row&7)<<4): conflict-free ds_read_b128.
// ---------------------------------------------------------------------------
__global__ __launch_bounds__(256) void gemm_kernel(const float* __restrict__ data,
                                                   const unsigned short* __restrict__ Wt,
                                                   unsigned short* __restrict__ uhat) {
    __shared__ alignas(16) char Ab[128 * 128];   // 128 rows x 64 bf16
    __shared__ alignas(16) char Bb[160 * 128];   // 160 rows x 64 bf16
    const int tid = threadIdx.x;
    const int lane = tid & 63;
    const int w = tid >> 6;
    const int b0 = blockIdx.x * 128;
    const int cc = blockIdx.y;
    const float* Abase = data + (long)b0 * (IC * ID) + cc * ID;
    const unsigned short* Bbase = Wt + (long)cc * (5 * OD16 * 64);

    f32x4 acc[2][10];
    #pragma unroll
    for (int i = 0; i < 2; ++i)
        #pragma unroll
        for (int j = 0; j < 10; ++j)
            acc[i][j] = (f32x4){0.f, 0.f, 0.f, 0.f};

    for (int s = 0; s < 5; ++s) {
        const int k0 = s * 64;
        const int kw = (s == 4) ? 32 : 64;
        __syncthreads();
        // stage A: 2048 granules (float4 global -> 4 bf16 = 8B LDS)
        #pragma unroll
        for (int jj = 0; jj < 8; ++jj) {
            int flat = jj * 256 + tid;
            int r = flat >> 4;
            int seg = flat & 15;
            if (seg * 4 < kw) {
                float4 v = *(const float4*)(Abase + (long)r * (IC * ID) + k0 + seg * 4);
                uint2 pk;
                pk.x = (unsigned)f2bf(v.x) | ((unsigned)f2bf(v.y) << 16);
                pk.y = (unsigned)f2bf(v.z) | ((unsigned)f2bf(v.w) << 16);
                int byte = (r * 128 + seg * 8) ^ ((r & 7) << 4);
                *(uint2*)(Ab + byte) = pk;
            }
        }
        // stage B: 1280 granules of 16B (already bf16, pre-padded)
        #pragma unroll
        for (int it = 0; it < 5; ++it) {
            int fg = it * 256 + tid;
            int n = fg >> 3;
            int g = fg & 7;
            uint4 val = *(const uint4*)(Bbase + (s * OD16 + n) * 64 + g * 8);
            int byte = (n * 128 + g * 16) ^ ((n & 7) << 4);
            *(uint4*)(Bb + byte) = val;
        }
        __syncthreads();
        const int nkc = (s == 4) ? 1 : 2;
        for (int kc = 0; kc < nkc; ++kc) {
            const int kb = (kc * 32 + ((lane >> 4) * 8)) * 2;  // byte offset in row
            bf16x8 af[2];
            #pragma unroll
            for (int mf = 0; mf < 2; ++mf) {
                int row = w * 32 + mf * 16 + (lane & 15);
                af[mf] = *(const bf16x8*)(Ab + ((row * 128 + kb) ^ ((row & 7) << 4)));
            }
            bf16x8 bfr[10];
            #pragma unroll
            for (int nf = 0; nf < 10; ++nf) {
                int n = nf * 16 + (lane & 15);
                bfr[nf] = *(const bf16x8*)(Bb + ((n * 128 + kb) ^ ((n & 7) << 4)));
            }
            #pragma unroll
            for (int mf = 0; mf < 2; ++mf)
                #pragma unroll
                for (int nf = 0; nf < 10; ++nf)
                    acc[mf][nf] = __builtin_amdgcn_mfma_f32_16x16x32_bf16(af[mf], bfr[nf], acc[mf][nf], 0, 0, 0);
        }
    }
    // epilogue: C/D layout col=lane&15 (N), row=(lane>>4)*4+reg (M)  [m89-verified]
    #pragma unroll
    for (int mf = 0; mf < 2; ++mf) {
        #pragma unroll
        for (int r = 0; r < 4; ++r) {
            int m = w * 32 + mf * 16 + ((lane >> 4) << 2) + r;
            unsigned short* up = uhat + (long)(b0 + m) * (IC * OD16) + cc * OD16 + (lane & 15);
            #pragma unroll
            for (int nf = 0; nf < 10; ++nf)
                up[nf * 16] = f2bf(acc[mf][nf][r]);
        }
    }
}

// ---------------------------------------------------------------------------
// K_u: b += a/8192; a = 0; c = softmax(b over i). 1 block x 320 threads.
// t = o*32 + i  -> i-groups are 32-lane aligned, shfl_xor stays in-group.
// ---------------------------------------------------------------------------
__global__ __launch_bounds__(320) void update_kernel(float* __restrict__ b_arr,
                                                     float* __restrict__ a_arr,
                                                     float* __restrict__ c_arr) {
    const int t = threadIdx.x;
    float bv = b_arr[t] + a_arr[t] * (1.0f / 8192.0f);
    b_arr[t] = bv;
    a_arr[t] = 0.f;
    float m = bv;
    #pragma unroll
    for (int off = 1; off < 32; off <<= 1) m = fmaxf(m, __shfl_xor(m, off, 64));
    float e = expf(bv - m);
    float ssum = e;
    #pragma unroll
    for (int off = 1; off < 32; off <<= 1) ssum += __shfl_xor(ssum, off, 64);
    c_arr[t] = e / ssum;
}

// ---------------------------------------------------------------------------
// K_r: one wave per batch row. Stage row (32x160 bf16) in LDS with padded
// row stride 164 elems (328B -> 2-way banks, free). Phase2: 40 lanes compute
// v od-quads. Phase3: 320 (i,o) tasks over 64 lanes x 5; per-lane register
// accumulation of a, single atomicAdd per task at the end.
// ---------------------------------------------------------------------------
template <int COMPUTE_A, int WRITE_V>
__global__ __launch_bounds__(256) void route_kernel(const unsigned short* __restrict__ uhat,
                                                    const float* __restrict__ c_coef,
                                                    float* __restrict__ a_out,
                                                    float* __restrict__ v_out) {
    constexpr int RS = 164;
    __shared__ alignas(16) unsigned short u_lds[4][32 * RS];
    __shared__ alignas(16) float v_lds[4][160];
    __shared__ float c_sh[320];
    const int tid = threadIdx.x;
    for (int t = tid; t < 320; t += 256) c_sh[t] = c_coef[t];
    __syncthreads();
    const int w = tid >> 6;
    const int lane = tid & 63;
    float areg[5] = {0.f, 0.f, 0.f, 0.f, 0.f};
    const int step = gridDim.x * 4;
    for (int row = blockIdx.x * 4 + w; row < NB; row += step) {
        asm volatile("" ::: "memory");  // keep prev-iter LDS reads before new writes
        const unsigned short* src = uhat + (long)row * (IC * OD16);
        #pragma unroll
        for (int ch = 0; ch < 10; ++ch) {
            int e = ch * 512 + lane * 8;
            uint4 val = *(const uint4*)(src + e);
            int i = e / 160;
            int od = e - i * 160;
            unsigned short* dst = &u_lds[w][i * RS + od];
            *(uint2*)(dst) = make_uint2(val.x, val.y);
            *(uint2*)(dst + 4) = make_uint2(val.z, val.w);
        }
        asm volatile("s_waitcnt lgkmcnt(0)" ::: "memory");  // cross-lane LDS visibility (per-wave buffer)
        if (lane < 40) {
            const int q = lane;
            const int o = q >> 2;
            float4 sv = {0.f, 0.f, 0.f, 0.f};
            #pragma unroll
            for (int i = 0; i < 32; ++i) {
                ushort4 uu = *(const ushort4*)(&u_lds[w][i * RS + q * 4]);
                float ci = c_sh[o * 32 + i];
                sv.x += ci * bf2f(uu.x);
                sv.y += ci * bf2f(uu.y);
                sv.z += ci * bf2f(uu.z);
                sv.w += ci * bf2f(uu.w);
            }
            if (WRITE_V) *(float4*)(v_out + (long)row * 160 + q * 4) = sv;
            if (COMPUTE_A) *(float4*)(&v_lds[w][q * 4]) = sv;
        }
        if (COMPUTE_A) {
            asm volatile("s_waitcnt lgkmcnt(0)" ::: "memory");
            #pragma unroll
            for (int s5 = 0; s5 < 5; ++s5) {
                int t5 = lane + 64 * s5;
                int i = t5 & 31;
                int oo = t5 >> 5;
                const unsigned short* up = &u_lds[w][i * RS + oo * 16];
                const float* vp = &v_lds[w][oo * 16];
                float accv = 0.f;
                #pragma unroll
                for (int dd = 0; dd < 16; dd += 4) {
                    ushort4 uu = *(const ushort4*)(up + dd);
                    float4 vv = *(const float4*)(vp + dd);
                    float p0 = bf2f(uu.x) * vv.x;
                    float p1 = bf2f(uu.y) * vv.y;
                    float p2 = bf2f(uu.z) * vv.z;
                    float p3 = bf2f(uu.w) * vv.w;
                    accv += p0 * p0 + p1 * p1 + p2 * p2 + p3 * p3;
                }
                areg[s5] += sqrtf(accv);
            }
        }
    }
    if (COMPUTE_A) {
        #pragma unroll
        for (int s5 = 0; s5 < 5; ++s5) {
            int t5 = lane + 64 * s5;
            int i = t5 & 31;
            int oo = t5 >> 5;
            atomicAdd(a_out + (oo * 32 + i), areg[s5]);
        }
    }
}

// ---------------------------------------------------------------------------
extern "C" void kernel_launch(void* const* d_in, const int* in_sizes, int n_in,
                              void* d_out, int out_size, void* d_ws, size_t ws_size,
                              hipStream_t stream) {
    const float* data = (const float*)d_in[0];
    const float* W = (const float*)d_in[1];
    float* out = (float*)d_out;
    char* ws = (char*)d_ws;

    unsigned short* uhat = (unsigned short*)ws;           // 83,886,080 B
    size_t off = (size_t)NB * IC * OD16 * 2;
    unsigned short* Wt = (unsigned short*)(ws + off);     // 3,276,800 B
    off += 32L * 5 * 64 * OD16 * 2;
    float* b_arr = (float*)(ws + off); off += 1280;
    float* a_arr = (float*)(ws + off); off += 1280;
    float* c_arr = (float*)(ws + off); off += 1280;
    // total ws use ~87.2 MB

    hipLaunchKernelGGL(prep_kernel, dim3(800), dim3(256), 0, stream, W, Wt, b_arr);
    hipLaunchKernelGGL(gemm_kernel, dim3(64, 32), dim3(256), 0, stream, data, Wt, uhat);
    for (int it = 0; it < 3; ++it) {
        hipLaunchKernelGGL(update_kernel, dim3(1), dim3(320), 0, stream, b_arr, a_arr, c_arr);
        if (it < 2)
            hipLaunchKernelGGL((route_kernel<1, 0>), dim3(768), dim3(256), 0, stream,
                               uhat, c_arr, a_arr, out);
        else
            hipLaunchKernelGGL((route_kernel<0, 1>), dim3(768), dim3(256), 0, stream,
                               uhat, c_arr, a_arr, out);
    }
}

// Round 2
// 292.719 us; speedup vs baseline: 1.1629x; 1.1629x over previous
//
#include <hip/hip_runtime.h>

#define NB 8192     // batch
#define IC 32       // input capsules
#define ID 288      // input dims (K)
#define OD16 160    // OUT_CAPS*OUT_DIMS (N)

typedef __attribute__((ext_vector_type(8))) short bf16x8;
typedef __attribute__((ext_vector_type(4))) float f32x4;

__device__ __forceinline__ unsigned short f2bf(float f) {
    unsigned int u = __builtin_bit_cast(unsigned int, f);
    u = u + 0x7fffu + ((u >> 16) & 1u);   // round-to-nearest-even
    return (unsigned short)(u >> 16);
}
__device__ __forceinline__ float bf2f(unsigned short h) {
    return __builtin_bit_cast(float, ((unsigned int)h) << 16);
}

__device__ __forceinline__ void gld_lds16(const void* g, void* l) {
    __builtin_amdgcn_global_load_lds((const __attribute__((address_space(1))) unsigned int*)g,
                                     (__attribute__((address_space(3))) unsigned int*)l, 16, 0, 0);
}

// ---------------------------------------------------------------------------
// prep: one block per (c, s). LDS-transpose W's [kw x 160] f32 tile into
// bf16, then emit the "LDS image" WtImg[c][s][10240 shorts]: linear byte b
// holds granule (n = b>>7, g = ((b>>4)&7) ^ (n&7)) so that a linear
// global_load_lds write + XOR-swizzled ds_read in gemm reconstructs B.
// K padded 288->320 with zeros (s=4 granules g*8>=32).
// Block 0 additionally zeros a[3][320].
// ---------------------------------------------------------------------------
__global__ __launch_bounds__(256) void prep_kernel(const float* __restrict__ W,
                                                   unsigned short* __restrict__ WtImg,
                                                   float* __restrict__ a_arr) {
    __shared__ short tile[160 * 72];   // row n: 64 k-shorts (+pad), 144B stride (16B-aligned)
    const int bx = blockIdx.x;
    const int c = bx / 5;
    const int s = bx - c * 5;
    const int t = threadIdx.x;
    if (bx == 0) {
        for (int i = t; i < 960; i += 256) a_arr[i] = 0.f;
    }
    const int kw = (s == 4) ? 32 : 64;
    const int nel = kw * 160;
    for (int idx = t; idx < nel; idx += 256) {
        int k = idx / 160;
        int n = idx - k * 160;
        tile[n * 72 + k] = (short)f2bf(W[((long)c * ID + s * 64 + k) * OD16 + n]);
    }
    __syncthreads();
    unsigned short* dst = WtImg + ((long)c * 5 + s) * 10240;
    for (int p = t; p < 1280; p += 256) {
        int n = p >> 3;
        int g = (p & 7) ^ (n & 7);
        uint4 val = make_uint4(0u, 0u, 0u, 0u);
        if (g * 8 < kw) val = *(const uint4*)&tile[n * 72 + g * 8];
        *(uint4*)(dst + p * 8) = val;
    }
}

// ---------------------------------------------------------------------------
// gemm: u_hat[b][c][od] = data[b][c][:] @ W[c][:][od], bf16 MFMA 16x16x32.
// Block 256 thr (4 waves), tile 128(M) x 160(N), BK=64, 5 stages (K pad 320).
// A: direct global->reg fragment loads (no LDS, no A barrier).
// B: double-buffered LDS via global_load_lds (DMA in flight across compute),
//    one barrier per stage. Epilogue stages C through the dead B buffer for
//    coalesced 16B stores.
// ---------------------------------------------------------------------------
__global__ __launch_bounds__(256) void gemm_kernel(const float* __restrict__ data,
                                                   const unsigned short* __restrict__ WtImg,
                                                   unsigned short* __restrict__ uhat) {
    __shared__ alignas(16) char Bb[2][20480];
    const int tid = threadIdx.x;
    const int lane = tid & 63;
    const int w = tid >> 6;
    const int q = lane >> 4;     // 0..3
    const int r = lane & 15;
    const int b0 = blockIdx.x * 128;
    const int cc = blockIdx.y;

    const float* A0 = data + (long)(b0 + w * 32 + r) * (IC * ID) + cc * ID;  // mf=0 row
    const float* A1 = A0 + 16 * (IC * ID);                                   // mf=1 row
    const unsigned short* Wc = WtImg + (long)cc * 51200;

    f32x4 acc[2][10];
    #pragma unroll
    for (int i = 0; i < 2; ++i)
        #pragma unroll
        for (int j = 0; j < 10; ++j)
            acc[i][j] = (f32x4){0.f, 0.f, 0.f, 0.f};

    auto issueB = [&](int buf, int s) {
        const unsigned short* src = Wc + s * 10240 + (w * 5) * 512 + lane * 8;
        char* dst = &Bb[buf][(w * 5) * 1024];
        #pragma unroll
        for (int j = 0; j < 5; ++j)
            gld_lds16(src + j * 512, dst + j * 1024);
    };

    int cur = 0;
    issueB(0, 0);
    __syncthreads();   // compiler drains vmcnt before barrier -> Bb[0] ready

    for (int s = 0; s < 5; ++s) {
        if (s < 4) issueB(cur ^ 1, s + 1);   // next-stage DMA in flight over compute
        const int nkc = (s == 4) ? 1 : 2;
        // issue all A fragment loads for this stage up front
        float4 av[2][2][2];   // [mf][kc][half]
        #pragma unroll
        for (int kc = 0; kc < 2; ++kc) {
            if (kc < nkc) {
                const int k = s * 64 + kc * 32 + q * 8;
                av[0][kc][0] = *(const float4*)(A0 + k);
                av[0][kc][1] = *(const float4*)(A0 + k + 4);
                av[1][kc][0] = *(const float4*)(A1 + k);
                av[1][kc][1] = *(const float4*)(A1 + k + 4);
            }
        }
        #pragma unroll
        for (int kc = 0; kc < 2; ++kc) {
            if (kc < nkc) {
                const int kb = kc * 64 + q * 16;   // byte offset within 128B row
                bf16x8 bfr[10];
                #pragma unroll
                for (int nf = 0; nf < 10; ++nf) {
                    const int n = nf * 16 + r;
                    bfr[nf] = *(const bf16x8*)(&Bb[cur][(n * 128 + kb) ^ ((n & 7) << 4)]);
                }
                bf16x8 af[2];
                #pragma unroll
                for (int mf = 0; mf < 2; ++mf) {
                    const float* fv = (const float*)&av[mf][kc][0];
                    #pragma unroll
                    for (int e = 0; e < 8; ++e)
                        af[mf][e] = (short)f2bf(fv[e]);
                }
                #pragma unroll
                for (int mf = 0; mf < 2; ++mf)
                    #pragma unroll
                    for (int nf = 0; nf < 10; ++nf)
                        acc[mf][nf] = __builtin_amdgcn_mfma_f32_16x16x32_bf16(af[mf], bfr[nf], acc[mf][nf], 0, 0, 0);
            }
        }
        __syncthreads();   // all waves done with Bb[cur]; Bb[cur^1] DMA drained
        cur ^= 1;
    }

    // epilogue: C/D layout col=lane&15 (N), row=q*4+reg (M)  [m89-verified]
    short* eb = (short*)&Bb[0][0];   // [128][160] shorts = 40960B
    #pragma unroll
    for (int mf = 0; mf < 2; ++mf)
        #pragma unroll
        for (int rr = 0; rr < 4; ++rr) {
            const int m = w * 32 + mf * 16 + (q << 2) + rr;
            #pragma unroll
            for (int nf = 0; nf < 10; ++nf)
                eb[m * 160 + nf * 16 + r] = (short)f2bf(acc[mf][nf][rr]);
        }
    __syncthreads();
    #pragma unroll
    for (int j = 0; j < 10; ++j) {
        const int chunk = j * 256 + tid;
        const int row = chunk / 20;
        const int p = chunk - row * 20;
        *(uint4*)(uhat + (long)(b0 + row) * (IC * OD16) + cc * OD16 + p * 8) =
            *(const uint4*)(eb + row * 160 + p * 8);
    }
}

// ---------------------------------------------------------------------------
// route: one wave per batch row. Each block first computes c = softmax over i
// of (sum_{j<n_prev} a[j])/8192 locally (b never materialized; b0=0 gives the
// uniform first-iteration c automatically). Then per row: stage 32x160 bf16
// in LDS (stride 164 -> 2-way banks, free), 40 lanes compute v od-quads,
// then 320 (i,o) agreement tasks with register accumulation + one atomicAdd.
// ---------------------------------------------------------------------------
template <int COMPUTE_A, int WRITE_V>
__global__ __launch_bounds__(256) void route_kernel(const unsigned short* __restrict__ uhat,
                                                    const float* __restrict__ a_all,
                                                    int n_prev,
                                                    float* __restrict__ a_out,
                                                    float* __restrict__ v_out) {
    constexpr int RS = 164;
    __shared__ alignas(16) unsigned short u_lds[4][32 * RS];
    __shared__ alignas(16) float v_lds[4][160];
    __shared__ float c_sh[320];
    const int tid = threadIdx.x;
    // --- in-block softmax over input capsules (groups of 32, lane-aligned) ---
    {
        float bv = 0.f;
        for (int j = 0; j < n_prev; ++j) bv += a_all[j * 320 + tid];
        bv *= (1.0f / 8192.0f);
        float m = bv;
        #pragma unroll
        for (int off = 1; off < 32; off <<= 1) m = fmaxf(m, __shfl_xor(m, off, 64));
        float e = __expf(bv - m);
        float ssum = e;
        #pragma unroll
        for (int off = 1; off < 32; off <<= 1) ssum += __shfl_xor(ssum, off, 64);
        c_sh[tid] = e / ssum;
    }
    if (tid < 64) {
        const int t2 = 256 + tid;
        float bv = 0.f;
        for (int j = 0; j < n_prev; ++j) bv += a_all[j * 320 + t2];
        bv *= (1.0f / 8192.0f);
        float m = bv;
        #pragma unroll
        for (int off = 1; off < 32; off <<= 1) m = fmaxf(m, __shfl_xor(m, off, 64));
        float e = __expf(bv - m);
        float ssum = e;
        #pragma unroll
        for (int off = 1; off < 32; off <<= 1) ssum += __shfl_xor(ssum, off, 64);
        c_sh[t2] = e / ssum;
    }
    __syncthreads();

    const int w = tid >> 6;
    const int lane = tid & 63;
    float areg[5] = {0.f, 0.f, 0.f, 0.f, 0.f};
    const int step = gridDim.x * 4;
    for (int row = blockIdx.x * 4 + w; row < NB; row += step) {
        asm volatile("" ::: "memory");  // keep prev-iter LDS reads before new writes
        const unsigned short* src = uhat + (long)row * (IC * OD16);
        #pragma unroll
        for (int ch = 0; ch < 10; ++ch) {
            int e = ch * 512 + lane * 8;
            uint4 val = *(const uint4*)(src + e);
            int i = e / 160;
            int od = e - i * 160;
            unsigned short* dst = &u_lds[w][i * RS + od];
            *(uint2*)(dst) = make_uint2(val.x, val.y);
            *(uint2*)(dst + 4) = make_uint2(val.z, val.w);
        }
        asm volatile("s_waitcnt lgkmcnt(0)" ::: "memory");  // per-wave LDS visibility
        if (lane < 40) {
            const int qq = lane;
            const int o = qq >> 2;
            float4 sv = {0.f, 0.f, 0.f, 0.f};
            #pragma unroll
            for (int i = 0; i < 32; ++i) {
                ushort4 uu = *(const ushort4*)(&u_lds[w][i * RS + qq * 4]);
                float ci = c_sh[o * 32 + i];
                sv.x += ci * bf2f(uu.x);
                sv.y += ci * bf2f(uu.y);
                sv.z += ci * bf2f(uu.z);
                sv.w += ci * bf2f(uu.w);
            }
            if (WRITE_V) *(float4*)(v_out + (long)row * 160 + qq * 4) = sv;
            if (COMPUTE_A) *(float4*)(&v_lds[w][qq * 4]) = sv;
        }
        if (COMPUTE_A) {
            asm volatile("s_waitcnt lgkmcnt(0)" ::: "memory");
            #pragma unroll
            for (int s5 = 0; s5 < 5; ++s5) {
                int t5 = lane + 64 * s5;
                int i = t5 & 31;
                int oo = t5 >> 5;
                const unsigned short* up = &u_lds[w][i * RS + oo * 16];
                const float* vp = &v_lds[w][oo * 16];
                float accv = 0.f;
                #pragma unroll
                for (int dd = 0; dd < 16; dd += 4) {
                    ushort4 uu = *(const ushort4*)(up + dd);
                    float4 vv = *(const float4*)(vp + dd);
                    float p0 = bf2f(uu.x) * vv.x;
                    float p1 = bf2f(uu.y) * vv.y;
                    float p2 = bf2f(uu.z) * vv.z;
                    float p3 = bf2f(uu.w) * vv.w;
                    accv += p0 * p0 + p1 * p1 + p2 * p2 + p3 * p3;
                }
                areg[s5] += sqrtf(accv);
            }
        }
    }
    if (COMPUTE_A) {
        #pragma unroll
        for (int s5 = 0; s5 < 5; ++s5) {
            int t5 = lane + 64 * s5;
            int i = t5 & 31;
            int oo = t5 >> 5;
            atomicAdd(a_out + (oo * 32 + i), areg[s5]);
        }
    }
}

// ---------------------------------------------------------------------------
extern "C" void kernel_launch(void* const* d_in, const int* in_sizes, int n_in,
                              void* d_out, int out_size, void* d_ws, size_t ws_size,
                              hipStream_t stream) {
    const float* data = (const float*)d_in[0];
    const float* W = (const float*)d_in[1];
    float* out = (float*)d_out;
    char* ws = (char*)d_ws;

    unsigned short* uhat = (unsigned short*)ws;           // 83,886,080 B
    size_t off = (size_t)NB * IC * OD16 * 2;
    unsigned short* WtImg = (unsigned short*)(ws + off);  // 3,276,800 B
    off += 32L * 5 * 10240 * 2;
    float* a_arr = (float*)(ws + off); off += 3 * 320 * 4;

    hipLaunchKernelGGL(prep_kernel, dim3(160), dim3(256), 0, stream, W, WtImg, a_arr);
    hipLaunchKernelGGL(gemm_kernel, dim3(64, 32), dim3(256), 0, stream, data, WtImg, uhat);
    hipLaunchKernelGGL((route_kernel<1, 0>), dim3(768), dim3(256), 0, stream,
                       uhat, a_arr, 0, a_arr + 0 * 320, out);
    hipLaunchKernelGGL((route_kernel<1, 0>), dim3(768), dim3(256), 0, stream,
                       uhat, a_arr, 1, a_arr + 1 * 320, out);
    hipLaunchKernelGGL((route_kernel<0, 1>), dim3(768), dim3(256), 0, stream,
                       uhat, a_arr, 2, a_arr + 2 * 320, out);
}